// Round 11
// baseline (244.955 us; speedup 1.0000x reference)
//
#include <hip/hip_runtime.h>
#include <math.h>

#define D_CH 2048
#define LSEQ 8192
#define T1 32
#define NC1 256          // LSEQ / T1
#define VSLAB 524288     // per-slab V floats (8192*64)

typedef __attribute__((ext_vector_type(8))) short bf16x8;
typedef __attribute__((ext_vector_type(4))) float f32x4;

__device__ __forceinline__ short f2bf(float x) {
  unsigned u = __float_as_uint(x);
  u += 0x7FFFu + ((u >> 16) & 1);       // round-to-nearest-even
  return (short)(u >> 16);
}

// ---------------------------------------------------------------------------
// fp32 4x4-register-tile 64x64 matmul helpers on LDS (numerically critical
// dA-power chain stays fp32: squaring DOUBLES relative exponent error, so
// bf16 squarings diverge — measured: 65% output error with bf16 chain).
// ---------------------------------------------------------------------------
__device__ __forceinline__ void mmzero(float acc[16]) {
#pragma unroll
  for (int t = 0; t < 16; ++t) acc[t] = 0.f;
}

template <int SZ>
__device__ __forceinline__ void mmld(float acc[16], const float* __restrict__ Z,
                                     int r0, int c0) {
#pragma unroll
  for (int i = 0; i < 4; ++i) {
    float4 z = *(const float4*)&Z[(r0 + i) * SZ + c0];
    acc[i * 4 + 0] = z.x; acc[i * 4 + 1] = z.y;
    acc[i * 4 + 2] = z.z; acc[i * 4 + 3] = z.w;
  }
}

template <int SX, int SY>
__device__ __forceinline__ void mac44(float acc[16], const float* __restrict__ Xb,
                                      const float* __restrict__ Yb, int r0, int c0) {
#pragma unroll 4
  for (int k = 0; k < 64; k += 4) {
    float4 x0 = *(const float4*)&Xb[(r0 + 0) * SX + k];
    float4 x1 = *(const float4*)&Xb[(r0 + 1) * SX + k];
    float4 x2 = *(const float4*)&Xb[(r0 + 2) * SX + k];
    float4 x3 = *(const float4*)&Xb[(r0 + 3) * SX + k];
    float4 y0 = *(const float4*)&Yb[(k + 0) * SY + c0];
    float4 y1 = *(const float4*)&Yb[(k + 1) * SY + c0];
    float4 y2 = *(const float4*)&Yb[(k + 2) * SY + c0];
    float4 y3 = *(const float4*)&Yb[(k + 3) * SY + c0];
#define MROW(i, xi) \
    acc[i * 4 + 0] += xi.x * y0.x + xi.y * y1.x + xi.z * y2.x + xi.w * y3.x; \
    acc[i * 4 + 1] += xi.x * y0.y + xi.y * y1.y + xi.z * y2.y + xi.w * y3.y; \
    acc[i * 4 + 2] += xi.x * y0.z + xi.y * y1.z + xi.z * y2.z + xi.w * y3.z; \
    acc[i * 4 + 3] += xi.x * y0.w + xi.y * y1.w + xi.z * y2.w + xi.w * y3.w;
    MROW(0, x0) MROW(1, x1) MROW(2, x2) MROW(3, x3)
#undef MROW
  }
}

template <int SZ>
__device__ __forceinline__ void mmst(float* Dst, const float acc[16], int r0, int c0) {
#pragma unroll
  for (int i = 0; i < 4; ++i)
    *(float4*)&Dst[(r0 + i) * SZ + c0] =
        make_float4(acc[i * 4 + 0], acc[i * 4 + 1], acc[i * 4 + 2], acc[i * 4 + 3]);
}

// ---------------------------------------------------------------------------
// main_kernel (r11):
//   block 0: prep — fp32 Q-chain (S8) -> invdT (delta*Q^T), dA = 2Q-I.
//   block 1: RECOMPUTES the identical Q-chain (same code path, same fp32
//     instruction sequence -> bitwise-identical dA; no cross-block race),
//     then the 9 fp32 squarings -> dA32, dA512.  This was scan1's block NC1:
//     nine serial 64^3 matmuls on one CU ~ 20-25 us pinning the scan1
//     dispatch; here it hides under vgemm's 42 us shadow (13 matmuls ~30 us).
//   blocks 2..: V[slab] = B @ X (bf16 MFMA, 32t x 64n tiles) — r9/r4
//     structure, measured best of four variants at ~42 us (dbuf r6/r7 and
//     barrier-free r10 all equal or worse; r10: 8-way bank conflicts, 65 KB
//     LDS occupancy collapse).  Stride 76: conflict-free (655K -> 128).
// ---------------------------------------------------------------------------
__global__ __launch_bounds__(256) void main_kernel(const float* __restrict__ X,
                                                   const float* __restrict__ A,
                                                   const float* __restrict__ B,
                                                   const float* __restrict__ logd,
                                                   float* __restrict__ invdT,
                                                   float* __restrict__ dAg,
                                                   float* __restrict__ dA32g,
                                                   float* __restrict__ dA512g,
                                                   float* __restrict__ V,
                                                   int KS) {
  __shared__ float smem[8704];           // 34.8 KB union (prep needs it all)
  const int tid = threadIdx.x;
  const int lane = tid & 63;
  const int w = tid >> 6;

  if (blockIdx.x < 2) {
    // ---------------- Q-chain (fp32): Q ~= inv(I - P), ||P|| <= ~0.12 ------
    float* bQ = smem;
    float* bP = smem + 4352;
    const int r0 = (tid >> 4) * 4, c0 = (tid & 15) * 4;
    const float delta = expf(logd[0]);
    const float half = 0.5f * delta;
    float accQ[16], accP[16];

    for (int idx = tid; idx < 4096; idx += 256) {
      int i = idx >> 6, j = idx & 63;
      float p = half * A[idx];
      bP[i * 68 + j] = p;
      bQ[i * 68 + j] = p + (i == j ? 1.f : 0.f);   // S2 = I + P
    }
    __syncthreads();
    // bP = P^2
    mmzero(accP); mac44<68, 68>(accP, bP, bP, r0, c0);
    __syncthreads();
    mmst<68>(bP, accP, r0, c0);
    __syncthreads();
    // 2 doublings: S4 = (I+P^2)S2 (+P^4), S8 = (I+P^4)S4.
#pragma unroll 1
    for (int s = 0; s < 2; ++s) {
      mmld<68>(accQ, bQ, r0, c0);
      mac44<68, 68>(accQ, bP, bQ, r0, c0);        // Q + P^k * Q
      if (s < 1) { mmzero(accP); mac44<68, 68>(accP, bP, bP, r0, c0); }
      __syncthreads();
      mmst<68>(bQ, accQ, r0, c0);
      if (s < 1) mmst<68>(bP, accP, r0, c0);
      __syncthreads();
    }

    if (blockIdx.x == 0) {
      // exports: invdT = delta*Q^T, dA = 2Q - I
      for (int idx = tid; idx < 4096; idx += 256) {
        int n = idx >> 6, m = idx & 63;
        float qv = bQ[n * 68 + m];
        invdT[m * 64 + n] = delta * qv;
        dAg[idx] = 2.f * qv - (n == m ? 1.f : 0.f);
      }
      return;
    }

    // block 1: dA = 2Q - I in place (element-wise), then 9 squarings.
    for (int idx = tid; idx < 4096; idx += 256) {
      int i = idx >> 6, j = idx & 63;
      bQ[i * 68 + j] = 2.f * bQ[i * 68 + j] - (i == j ? 1.f : 0.f);
    }
    __syncthreads();
    float acc[16];
    float* p = bQ; float* q = bP;
    for (int s = 1; s <= 9; ++s) {
      mmzero(acc); mac44<68, 68>(acc, p, p, r0, c0);
      if (s == 5) mmst<64>(dA32g, acc, r0, c0);
      if (s == 9) mmst<64>(dA512g, acc, r0, c0);
      mmst<68>(q, acc, r0, c0);
      __syncthreads();
      float* t = p; p = q; q = t;
    }
    return;
  }

  // ------------------------------ vgemm (bf16 MFMA) ------------------------
  const int b = blockIdx.x - 2;
  const int t0 = (b & 255) << 5;         // 256 t-tiles of 32
  const int slab = b >> 8;
  const int k0 = slab * KS;
  short* Xs = (short*)smem;              // [32][76] bf16  (t-major)
  short* Bs = (short*)smem + 2432;       // [64][76] bf16  (n-major)
  const int q = lane >> 4, r = lane & 15;
  const int hi = lane >> 5, tl = lane & 31;
  const int brow = lane >> 3;            // 0..7
  const int bkc = (lane & 7) * 8;        // 0..56
  const int wm = (w & 1) * 16;           // M-half of this wave
  const int wn = (w >> 1) * 32;          // N-half of this wave

  f32x4 acc[2];
#pragma unroll
  for (int j = 0; j < 2; ++j) acc[j] = (f32x4){0.f, 0.f, 0.f, 0.f};

  float xv[8];
  float bv[16];

#define LOADX(KK)                                                              \
  _Pragma("unroll")                                                            \
  for (int j = 0; j < 8; ++j)                                                  \
    xv[j] = X[(size_t)(k0 + (KK) + w * 16 + hi * 8 + j) * LSEQ + t0 + tl];

#define LOADB(KK)                                                              \
  _Pragma("unroll")                                                            \
  for (int pp = 0; pp < 2; ++pp) {                                             \
    int n = pp * 32 + w * 8 + brow;                                            \
    float4 f0 = *(const float4*)&B[(size_t)n * D_CH + k0 + (KK) + bkc];        \
    float4 f1 = *(const float4*)&B[(size_t)n * D_CH + k0 + (KK) + bkc + 4];    \
    bv[pp * 8 + 0] = f0.x; bv[pp * 8 + 1] = f0.y;                              \
    bv[pp * 8 + 2] = f0.z; bv[pp * 8 + 3] = f0.w;                              \
    bv[pp * 8 + 4] = f1.x; bv[pp * 8 + 5] = f1.y;                              \
    bv[pp * 8 + 6] = f1.z; bv[pp * 8 + 7] = f1.w;                              \
  }

  LOADX(0)
  LOADB(0)

  for (int kk = 0; kk < KS; kk += 64) {
    // cvt + LDS write of the tile staged in registers
    bf16x8 xp;
#pragma unroll
    for (int j = 0; j < 8; ++j) xp[j] = f2bf(xv[j]);
    *(bf16x8*)&Xs[tl * 76 + w * 16 + hi * 8] = xp;
#pragma unroll
    for (int pp = 0; pp < 2; ++pp) {
      bf16x8 bp8;
#pragma unroll
      for (int j = 0; j < 8; ++j) bp8[j] = f2bf(bv[pp * 8 + j]);
      *(bf16x8*)&Bs[(pp * 32 + w * 8 + brow) * 76 + bkc] = bp8;
    }
    __syncthreads();

    // prefetch next K-step into registers (overlaps MFMA + barrier)
    if (kk + 64 < KS) {
      LOADX(kk + 64)
      LOADB(kk + 64)
    }

#pragma unroll
    for (int ks = 0; ks < 64; ks += 32) {
      bf16x8 a = *(const bf16x8*)&Xs[(wm + r) * 76 + ks + q * 8];
#pragma unroll
      for (int j = 0; j < 2; ++j) {
        bf16x8 bb = *(const bf16x8*)&Bs[(wn + j * 16 + r) * 76 + ks + q * 8];
        acc[j] = __builtin_amdgcn_mfma_f32_16x16x32_bf16(a, bb, acc[j], 0, 0, 0);
      }
    }
    __syncthreads();
  }
#undef LOADX
#undef LOADB

  float* Vs = V + (size_t)slab * VSLAB;
#pragma unroll
  for (int j = 0; j < 2; ++j)
#pragma unroll
    for (int reg = 0; reg < 4; ++reg)
      Vs[(size_t)(t0 + wm + q * 4 + reg) * 64 + wn + j * 16 + r] = acc[j][reg];
}

// ---------------------------------------------------------------------------
// LDS-resident matvec: h'[lane] = u + M[lane][:] . hb[:]
// M stored with stride 68 -> bank (4*row+col)%32: the wave's 64 row reads
// spread across all 8 four-bank groups (structural floor); hb reads are
// same-address broadcasts (free).  Allocator-proof: rounds 1-3 proved the
// compiler refuses to keep a 64-float per-lane matrix row in VGPRs.
// ---------------------------------------------------------------------------
__device__ __forceinline__ float matvec_lds(const float* __restrict__ Mrow,
                                            const float* __restrict__ hb, float u) {
  float a0 = u, a1 = 0.f, a2 = 0.f, a3 = 0.f;
#pragma unroll
  for (int jj = 0; jj < 64; jj += 4) {
    float4 m = *(const float4*)&Mrow[jj];
    float4 hv = *(const float4*)&hb[jj];
    a0 += m.x * hv.x;
    a1 += m.y * hv.y;
    a2 += m.z * hv.z;
    a3 += m.w * hv.w;
  }
  return (a0 + a1) + (a2 + a3);
}

// stage a 64x64 fp32 matrix into [64][68]-padded LDS, 64-thread block.
__device__ __forceinline__ void stage_mat64(float* Mlds, const float* __restrict__ Mg,
                                            int lane) {
#pragma unroll
  for (int i = 0; i < 16; ++i) {
    int row = i * 4 + (lane >> 4);
    int col = (lane & 15) * 4;
    *(float4*)&Mlds[row * 68 + col] = *(const float4*)&Mg[row * 64 + col];
  }
  __syncthreads();
}

// ---------------------------------------------------------------------------
// scan1 (r11): blocks 0..NC1-1 only — U-chunk = invd applied to sum of V
// slabs, then wave 0 does the serial 32-step chunk summary (dA in padded
// LDS).  The dA-squaring straggler block moved to main_kernel block 1.
// ---------------------------------------------------------------------------
__global__ __launch_bounds__(256) void scan1_kernel(const float* __restrict__ V,
                                                    const float* __restrict__ invdT,
                                                    const float* __restrict__ dA,
                                                    float* __restrict__ U,
                                                    float* __restrict__ S,
                                                    int nslab) {
  __shared__ float smem[13056];
  const int tid = threadIdx.x;
  const int c = blockIdx.x;

  float* invs = smem;            // 4096
  float* Vs   = smem + 4096;     // 2048
  float* Us   = smem + 6144;     // 2048
  float* hs0  = smem + 8192;     // 64
  float* hs1  = smem + 8256;     // 64
  float* Md   = smem + 8320;     // 4352 ([64][68] padded dA)

  for (int idx = tid; idx < 4096; idx += 256) invs[idx] = invdT[idx];
  for (int idx = tid; idx < 4096; idx += 256)
    Md[(idx >> 6) * 68 + (idx & 63)] = dA[idx];
  for (int idx = tid; idx < 2048; idx += 256) {
    float v = 0.f;
    for (int s = 0; s < nslab; ++s) v += V[(size_t)s * VSLAB + (size_t)c * 2048 + idx];
    Vs[idx] = v;
  }
  __syncthreads();

  // transform: 2 rows x 4 cols per thread
  const int r0 = (tid >> 4) * 2, c0 = (tid & 15) * 4;
  float a0[4] = {0.f, 0.f, 0.f, 0.f}, a1[4] = {0.f, 0.f, 0.f, 0.f};
#pragma unroll 4
  for (int k = 0; k < 64; k += 4) {
    float4 v0 = *(const float4*)&Vs[r0 * 64 + k];
    float4 v1 = *(const float4*)&Vs[(r0 + 1) * 64 + k];
    float4 y0 = *(const float4*)&invs[(k + 0) * 64 + c0];
    float4 y1 = *(const float4*)&invs[(k + 1) * 64 + c0];
    float4 y2 = *(const float4*)&invs[(k + 2) * 64 + c0];
    float4 y3 = *(const float4*)&invs[(k + 3) * 64 + c0];
    a0[0] += v0.x * y0.x + v0.y * y1.x + v0.z * y2.x + v0.w * y3.x;
    a0[1] += v0.x * y0.y + v0.y * y1.y + v0.z * y2.y + v0.w * y3.y;
    a0[2] += v0.x * y0.z + v0.y * y1.z + v0.z * y2.z + v0.w * y3.z;
    a0[3] += v0.x * y0.w + v0.y * y1.w + v0.z * y2.w + v0.w * y3.w;
    a1[0] += v1.x * y0.x + v1.y * y1.x + v1.z * y2.x + v1.w * y3.x;
    a1[1] += v1.x * y0.y + v1.y * y1.y + v1.z * y2.y + v1.w * y3.y;
    a1[2] += v1.x * y0.z + v1.y * y1.z + v1.z * y2.z + v1.w * y3.z;
    a1[3] += v1.x * y0.w + v1.y * y1.w + v1.z * y2.w + v1.w * y3.w;
  }
  *(float4*)&Us[r0 * 64 + c0] = make_float4(a0[0], a0[1], a0[2], a0[3]);
  *(float4*)&Us[(r0 + 1) * 64 + c0] = make_float4(a1[0], a1[1], a1[2], a1[3]);
  *(float4*)&U[(size_t)(c * 32 + r0) * 64 + c0] = make_float4(a0[0], a0[1], a0[2], a0[3]);
  *(float4*)&U[(size_t)(c * 32 + r0 + 1) * 64 + c0] = make_float4(a1[0], a1[1], a1[2], a1[3]);
  __syncthreads();

  if (tid < 64) {
    const float* row = Md + tid * 68;
    float h = 0.f;
    hs0[tid] = 0.f;
    for (int t = 0; t < T1; ++t) {
      float u = Us[t * 64 + tid];
      h = matvec_lds(row, (t & 1) ? hs1 : hs0, u);
      ((t & 1) ? hs0 : hs1)[tid] = h;
    }
    S[c * 64 + tid] = h;
  }
}

// ---------------------------------------------------------------------------
// mid stage, split into 3 one-wave-per-block kernels (round-4 verified:
// took mid from 47.6 us to sub-visibility).
// ---------------------------------------------------------------------------
__global__ __launch_bounds__(64) void mid1_kernel(const float* __restrict__ S,
                                                  const float* __restrict__ dA32,
                                                  float* __restrict__ S2g) {
  __shared__ float M[64 * 68];
  __shared__ float hs[2][64];
  const int lane = threadIdx.x;
  const int g = blockIdx.x;
  stage_mat64(M, dA32, lane);
  const float* row = M + lane * 68;
  const float* in = S + g * 16 * 64;
  float h = 0.f;
  hs[0][lane] = 0.f;
  for (int t = 0; t < 16; ++t) {
    h = matvec_lds(row, hs[t & 1], in[t * 64 + lane]);
    hs[(t + 1) & 1][lane] = h;
  }
  S2g[g * 64 + lane] = h;
}

__global__ __launch_bounds__(64) void mid2_kernel(const float* __restrict__ S2g,
                                                  const float* __restrict__ dA512,
                                                  float* __restrict__ H2g) {
  __shared__ float M[64 * 68];
  __shared__ float hs[2][64];
  const int lane = threadIdx.x;
  stage_mat64(M, dA512, lane);
  const float* row = M + lane * 68;
  float h = 0.f;
  hs[0][lane] = 0.f;
  for (int t = 0; t < 16; ++t) {
    H2g[t * 64 + lane] = h;
    h = matvec_lds(row, hs[t & 1], S2g[t * 64 + lane]);
    hs[(t + 1) & 1][lane] = h;
  }
}

__global__ __launch_bounds__(64) void mid3_kernel(const float* __restrict__ S,
                                                  const float* __restrict__ dA32,
                                                  const float* __restrict__ H2g,
                                                  float* __restrict__ Hinit) {
  __shared__ float M[64 * 68];
  __shared__ float hs[2][64];
  const int lane = threadIdx.x;
  const int g = blockIdx.x;
  stage_mat64(M, dA32, lane);
  const float* row = M + lane * 68;
  const float* in = S + g * 16 * 64;
  float h = H2g[g * 64 + lane];
  hs[0][lane] = h;
  for (int t = 0; t < 16; ++t) {
    Hinit[(g * 16 + t) * 64 + lane] = h;
    h = matvec_lds(row, hs[t & 1], in[t * 64 + lane]);
    hs[(t + 1) & 1][lane] = h;
  }
}

// ---------------------------------------------------------------------------
// scan2: one wave/block, full-state expansion, dA staged in padded LDS,
// 4-deep prefetch ring on U.
// ---------------------------------------------------------------------------
__global__ __launch_bounds__(64) void scan2_kernel(const float* __restrict__ U,
                                                   const float* __restrict__ dA,
                                                   const float* __restrict__ Hinit,
                                                   float* __restrict__ Ht) {
  __shared__ float M[64 * 68];
  __shared__ float hs[2][64];
  const int tid = threadIdx.x;
  const int c = blockIdx.x;
  stage_mat64(M, dA, tid);
  const float* row = M + tid * 68;
  float h = Hinit[c * 64 + tid];
  hs[0][tid] = h;
  const float* inc = U + (size_t)c * T1 * 64;
  float* outc = Ht + (size_t)c * T1 * 64;
  float up[4];
#pragma unroll
  for (int i = 0; i < 4; ++i) up[i] = inc[i * 64 + tid];

  for (int t = 0; t < T1; ++t) {
    float u = up[t & 3];
    if (t + 4 < T1) up[t & 3] = inc[(t + 4) * 64 + tid];
    h = matvec_lds(row, hs[t & 1], u);
    hs[(t + 1) & 1][tid] = h;
    outc[t * 64 + tid] = h;
  }
}

// ---------------------------------------------------------------------------
// out: Y[d][t] = (C @ Ht^T)[d][t] + Dp[d]*X[d][t]  via bf16 MFMA (K = 64).
// r4 epilogue (measured-best total); stride 76 for conflict-free MFMA reads.
// ---------------------------------------------------------------------------
__global__ __launch_bounds__(256) void out_kernel(const float* __restrict__ X,
                                                  const float* __restrict__ C,
                                                  const float* __restrict__ Dp,
                                                  const float* __restrict__ Ht,
                                                  float* __restrict__ Y) {
  __shared__ short Cs[64 * 76];      // [d][n] bf16
  __shared__ short Hs[64 * 76];      // [t][n] bf16
  const int tid = threadIdx.x;
  const int lane = tid & 63, w = tid >> 6;
  const int t0 = blockIdx.x * 64;
  const int d0 = blockIdx.y * 64;
  const int q = lane >> 4, r = lane & 15;
  const int brow = lane >> 3, bkc = (lane & 7) * 8;

#pragma unroll
  for (int p = 0; p < 2; ++p) {
    int row = p * 32 + w * 8 + brow;
    float4 c0 = *(const float4*)&C[(size_t)(d0 + row) * 64 + bkc];
    float4 c1 = *(const float4*)&C[(size_t)(d0 + row) * 64 + bkc + 4];
    float4 h0 = *(const float4*)&Ht[(size_t)(t0 + row) * 64 + bkc];
    float4 h1 = *(const float4*)&Ht[(size_t)(t0 + row) * 64 + bkc + 4];
    bf16x8 cv, hv;
    cv[0] = f2bf(c0.x); cv[1] = f2bf(c0.y); cv[2] = f2bf(c0.z); cv[3] = f2bf(c0.w);
    cv[4] = f2bf(c1.x); cv[5] = f2bf(c1.y); cv[6] = f2bf(c1.z); cv[7] = f2bf(c1.w);
    hv[0] = f2bf(h0.x); hv[1] = f2bf(h0.y); hv[2] = f2bf(h0.z); hv[3] = f2bf(h0.w);
    hv[4] = f2bf(h1.x); hv[5] = f2bf(h1.y); hv[6] = f2bf(h1.z); hv[7] = f2bf(h1.w);
    *(bf16x8*)&Cs[row * 76 + bkc] = cv;
    *(bf16x8*)&Hs[row * 76 + bkc] = hv;
  }
  __syncthreads();

  f32x4 acc[4];
#pragma unroll
  for (int j = 0; j < 4; ++j) acc[j] = (f32x4){0.f, 0.f, 0.f, 0.f};
#pragma unroll
  for (int ks = 0; ks < 64; ks += 32) {
    bf16x8 a = *(const bf16x8*)&Cs[(w * 16 + r) * 76 + ks + q * 8];
#pragma unroll
    for (int j = 0; j < 4; ++j) {
      bf16x8 bb = *(const bf16x8*)&Hs[(j * 16 + r) * 76 + ks + q * 8];
      acc[j] = __builtin_amdgcn_mfma_f32_16x16x32_bf16(a, bb, acc[j], 0, 0, 0);
    }
  }

#pragma unroll
  for (int reg = 0; reg < 4; ++reg) {
    int d = d0 + w * 16 + q * 4 + reg;
    float dp = Dp[d];
#pragma unroll
    for (int j = 0; j < 4; ++j) {
      int t = t0 + j * 16 + r;
      size_t off = (size_t)d * LSEQ + t;
      Y[off] = acc[j][reg] + dp * X[off];
    }
  }
}

// ---------------------------------------------------------------------------
extern "C" void kernel_launch(void* const* d_in, const int* in_sizes, int n_in,
                              void* d_out, int out_size, void* d_ws, size_t ws_size,
                              hipStream_t stream) {
  const float* X  = (const float*)d_in[0];
  const float* A  = (const float*)d_in[1];
  const float* B  = (const float*)d_in[2];
  const float* Cm = (const float*)d_in[3];
  const float* Dp = (const float*)d_in[4];
  const float* ld = (const float*)d_in[5];
  float* out = (float*)d_out;
  float* ws = (float*)d_ws;

  // 4 K-slabs if workspace allows (10.2 MB), else 2 (6.2 MB)
  const size_t need4 =
      (size_t)(16384 + 4 * VSLAB + VSLAB + 16384 + 16384 + 2048) * 4;
  const int nslab = (ws_size >= need4) ? 4 : 2;

  float* invdT = ws;                       // 4096
  float* dA    = ws + 4096;                // 4096
  float* dA32  = ws + 8192;                // 4096
  float* dA512 = ws + 12288;               // 4096
  float* V     = ws + 16384;               // nslab * 524288
  float* U     = V + (size_t)nslab * VSLAB; // 524288
  float* S     = U + VSLAB;                // 16384
  float* Hinit = S + 16384;                // 16384
  float* S2g   = Hinit + 16384;            // 1024
  float* H2g   = S2g + 1024;               // 1024
  float* Ht    = V;                         // overlay: V dead after scan1

  main_kernel<<<nslab * 256 + 2, 256, 0, stream>>>(X, A, B, ld, invdT, dA,
                                                   dA32, dA512, V, 2048 / nslab);
  scan1_kernel<<<NC1, 256, 0, stream>>>(V, invdT, dA, U, S, nslab);
  mid1_kernel<<<16, 64, 0, stream>>>(S, dA32, S2g);
  mid2_kernel<<<1, 64, 0, stream>>>(S2g, dA512, H2g);
  mid3_kernel<<<16, 64, 0, stream>>>(S, dA32, H2g, Hinit);
  scan2_kernel<<<NC1, 64, 0, stream>>>(U, dA, Hinit, Ht);
  out_kernel<<<dim3(128, 32), 256, 0, stream>>>(X, Cm, Dp, Ht, out);
}

// Round 12
// 235.650 us; speedup vs baseline: 1.0395x; 1.0395x over previous
//
#include <hip/hip_runtime.h>
#include <math.h>

#define D_CH 2048
#define LSEQ 8192
#define T1 32
#define NC1 256          // LSEQ / T1
#define VSLAB 524288     // per-slab V floats (8192*64)

typedef __attribute__((ext_vector_type(8))) short bf16x8;
typedef __attribute__((ext_vector_type(4))) float f32x4;

__device__ __forceinline__ short f2bf(float x) {
  unsigned u = __float_as_uint(x);
  u += 0x7FFFu + ((u >> 16) & 1);       // round-to-nearest-even
  return (short)(u >> 16);
}

// ---------------------------------------------------------------------------
// fp32 4x4-register-tile 64x64 matmul helpers on LDS (numerically critical
// dA-power chain stays fp32: squaring DOUBLES relative exponent error, so
// bf16 squarings diverge — measured: 65% output error with bf16 chain).
// Single-CU 64^3 matmul cost ~3.8-4.2 us (calibrated r11: 13 matmuls = 55us).
// ---------------------------------------------------------------------------
__device__ __forceinline__ void mmzero(float acc[16]) {
#pragma unroll
  for (int t = 0; t < 16; ++t) acc[t] = 0.f;
}

template <int SZ>
__device__ __forceinline__ void mmld(float acc[16], const float* __restrict__ Z,
                                     int r0, int c0) {
#pragma unroll
  for (int i = 0; i < 4; ++i) {
    float4 z = *(const float4*)&Z[(r0 + i) * SZ + c0];
    acc[i * 4 + 0] = z.x; acc[i * 4 + 1] = z.y;
    acc[i * 4 + 2] = z.z; acc[i * 4 + 3] = z.w;
  }
}

template <int SX, int SY>
__device__ __forceinline__ void mac44(float acc[16], const float* __restrict__ Xb,
                                      const float* __restrict__ Yb, int r0, int c0) {
#pragma unroll 4
  for (int k = 0; k < 64; k += 4) {
    float4 x0 = *(const float4*)&Xb[(r0 + 0) * SX + k];
    float4 x1 = *(const float4*)&Xb[(r0 + 1) * SX + k];
    float4 x2 = *(const float4*)&Xb[(r0 + 2) * SX + k];
    float4 x3 = *(const float4*)&Xb[(r0 + 3) * SX + k];
    float4 y0 = *(const float4*)&Yb[(k + 0) * SY + c0];
    float4 y1 = *(const float4*)&Yb[(k + 1) * SY + c0];
    float4 y2 = *(const float4*)&Yb[(k + 2) * SY + c0];
    float4 y3 = *(const float4*)&Yb[(k + 3) * SY + c0];
#define MROW(i, xi) \
    acc[i * 4 + 0] += xi.x * y0.x + xi.y * y1.x + xi.z * y2.x + xi.w * y3.x; \
    acc[i * 4 + 1] += xi.x * y0.y + xi.y * y1.y + xi.z * y2.y + xi.w * y3.y; \
    acc[i * 4 + 2] += xi.x * y0.z + xi.y * y1.z + xi.z * y2.z + xi.w * y3.z; \
    acc[i * 4 + 3] += xi.x * y0.w + xi.y * y1.w + xi.z * y2.w + xi.w * y3.w;
    MROW(0, x0) MROW(1, x1) MROW(2, x2) MROW(3, x3)
#undef MROW
  }
}

template <int SZ>
__device__ __forceinline__ void mmst(float* Dst, const float acc[16], int r0, int c0) {
#pragma unroll
  for (int i = 0; i < 4; ++i)
    *(float4*)&Dst[(r0 + i) * SZ + c0] =
        make_float4(acc[i * 4 + 0], acc[i * 4 + 1], acc[i * 4 + 2], acc[i * 4 + 3]);
}

// ---------------------------------------------------------------------------
// main_kernel (r12 — straggler split):
//   block 0: prep — fp32 Q-chain (S8) -> invdT (delta*Q^T), dA = 2Q-I.
//   block 1: recompute Q-chain (bitwise-identical dA), then squarings s=1..5
//     -> dA32 ONLY.  9 matmuls ~ 34-38 us < vgemm's 42 us shadow (r11's 13
//     matmuls = 55 us pinned the dispatch — calibrated ~4 us/matmul).
//   blocks 2..: V[slab] = B @ X (bf16 MFMA, 32t x 64n tiles) — r9/r4
//     structure, measured best of four staging variants (~42 us; dbuf r6/r7
//     and barrier-free r10 equal or worse).  Stride 76: conflict-free.
//   The dA32->dA512 tail (4 matmuls) moved to scan1 block NC1 (~15 us there,
//   vs 34 us when the whole chain lived in scan1 — r9).
// ---------------------------------------------------------------------------
__global__ __launch_bounds__(256) void main_kernel(const float* __restrict__ X,
                                                   const float* __restrict__ A,
                                                   const float* __restrict__ B,
                                                   const float* __restrict__ logd,
                                                   float* __restrict__ invdT,
                                                   float* __restrict__ dAg,
                                                   float* __restrict__ dA32g,
                                                   float* __restrict__ V,
                                                   int KS) {
  __shared__ float smem[8704];           // 34.8 KB union (prep needs it all)
  const int tid = threadIdx.x;
  const int lane = tid & 63;
  const int w = tid >> 6;

  if (blockIdx.x < 2) {
    // ---------------- Q-chain (fp32): Q ~= inv(I - P), ||P|| <= ~0.12 ------
    float* bQ = smem;
    float* bP = smem + 4352;
    const int r0 = (tid >> 4) * 4, c0 = (tid & 15) * 4;
    const float delta = expf(logd[0]);
    const float half = 0.5f * delta;
    float accQ[16], accP[16];

    for (int idx = tid; idx < 4096; idx += 256) {
      int i = idx >> 6, j = idx & 63;
      float p = half * A[idx];
      bP[i * 68 + j] = p;
      bQ[i * 68 + j] = p + (i == j ? 1.f : 0.f);   // S2 = I + P
    }
    __syncthreads();
    // bP = P^2
    mmzero(accP); mac44<68, 68>(accP, bP, bP, r0, c0);
    __syncthreads();
    mmst<68>(bP, accP, r0, c0);
    __syncthreads();
    // 2 doublings: S4 = (I+P^2)S2 (+P^4), S8 = (I+P^4)S4.
#pragma unroll 1
    for (int s = 0; s < 2; ++s) {
      mmld<68>(accQ, bQ, r0, c0);
      mac44<68, 68>(accQ, bP, bQ, r0, c0);        // Q + P^k * Q
      if (s < 1) { mmzero(accP); mac44<68, 68>(accP, bP, bP, r0, c0); }
      __syncthreads();
      mmst<68>(bQ, accQ, r0, c0);
      if (s < 1) mmst<68>(bP, accP, r0, c0);
      __syncthreads();
    }

    if (blockIdx.x == 0) {
      // exports: invdT = delta*Q^T, dA = 2Q - I
      for (int idx = tid; idx < 4096; idx += 256) {
        int n = idx >> 6, m = idx & 63;
        float qv = bQ[n * 68 + m];
        invdT[m * 64 + n] = delta * qv;
        dAg[idx] = 2.f * qv - (n == m ? 1.f : 0.f);
      }
      return;
    }

    // block 1: dA = 2Q - I in place (element-wise), then 5 squarings -> dA32.
    for (int idx = tid; idx < 4096; idx += 256) {
      int i = idx >> 6, j = idx & 63;
      bQ[i * 68 + j] = 2.f * bQ[i * 68 + j] - (i == j ? 1.f : 0.f);
    }
    __syncthreads();
    float acc[16];
    float* p = bQ; float* q = bP;
    for (int s = 1; s <= 5; ++s) {
      mmzero(acc); mac44<68, 68>(acc, p, p, r0, c0);
      if (s == 5) mmst<64>(dA32g, acc, r0, c0);
      mmst<68>(q, acc, r0, c0);
      __syncthreads();
      float* t = p; p = q; q = t;
    }
    return;
  }

  // ------------------------------ vgemm (bf16 MFMA) ------------------------
  const int b = blockIdx.x - 2;
  const int t0 = (b & 255) << 5;         // 256 t-tiles of 32
  const int slab = b >> 8;
  const int k0 = slab * KS;
  short* Xs = (short*)smem;              // [32][76] bf16  (t-major)
  short* Bs = (short*)smem + 2432;       // [64][76] bf16  (n-major)
  const int q = lane >> 4, r = lane & 15;
  const int hi = lane >> 5, tl = lane & 31;
  const int brow = lane >> 3;            // 0..7
  const int bkc = (lane & 7) * 8;        // 0..56
  const int wm = (w & 1) * 16;           // M-half of this wave
  const int wn = (w >> 1) * 32;          // N-half of this wave

  f32x4 acc[2];
#pragma unroll
  for (int j = 0; j < 2; ++j) acc[j] = (f32x4){0.f, 0.f, 0.f, 0.f};

  float xv[8];
  float bv[16];

#define LOADX(KK)                                                              \
  _Pragma("unroll")                                                            \
  for (int j = 0; j < 8; ++j)                                                  \
    xv[j] = X[(size_t)(k0 + (KK) + w * 16 + hi * 8 + j) * LSEQ + t0 + tl];

#define LOADB(KK)                                                              \
  _Pragma("unroll")                                                            \
  for (int pp = 0; pp < 2; ++pp) {                                             \
    int n = pp * 32 + w * 8 + brow;                                            \
    float4 f0 = *(const float4*)&B[(size_t)n * D_CH + k0 + (KK) + bkc];        \
    float4 f1 = *(const float4*)&B[(size_t)n * D_CH + k0 + (KK) + bkc + 4];    \
    bv[pp * 8 + 0] = f0.x; bv[pp * 8 + 1] = f0.y;                              \
    bv[pp * 8 + 2] = f0.z; bv[pp * 8 + 3] = f0.w;                              \
    bv[pp * 8 + 4] = f1.x; bv[pp * 8 + 5] = f1.y;                              \
    bv[pp * 8 + 6] = f1.z; bv[pp * 8 + 7] = f1.w;                              \
  }

  LOADX(0)
  LOADB(0)

  for (int kk = 0; kk < KS; kk += 64) {
    // cvt + LDS write of the tile staged in registers
    bf16x8 xp;
#pragma unroll
    for (int j = 0; j < 8; ++j) xp[j] = f2bf(xv[j]);
    *(bf16x8*)&Xs[tl * 76 + w * 16 + hi * 8] = xp;
#pragma unroll
    for (int pp = 0; pp < 2; ++pp) {
      bf16x8 bp8;
#pragma unroll
      for (int j = 0; j < 8; ++j) bp8[j] = f2bf(bv[pp * 8 + j]);
      *(bf16x8*)&Bs[(pp * 32 + w * 8 + brow) * 76 + bkc] = bp8;
    }
    __syncthreads();

    // prefetch next K-step into registers (overlaps MFMA + barrier)
    if (kk + 64 < KS) {
      LOADX(kk + 64)
      LOADB(kk + 64)
    }

#pragma unroll
    for (int ks = 0; ks < 64; ks += 32) {
      bf16x8 a = *(const bf16x8*)&Xs[(wm + r) * 76 + ks + q * 8];
#pragma unroll
      for (int j = 0; j < 2; ++j) {
        bf16x8 bb = *(const bf16x8*)&Bs[(wn + j * 16 + r) * 76 + ks + q * 8];
        acc[j] = __builtin_amdgcn_mfma_f32_16x16x32_bf16(a, bb, acc[j], 0, 0, 0);
      }
    }
    __syncthreads();
  }
#undef LOADX
#undef LOADB

  float* Vs = V + (size_t)slab * VSLAB;
#pragma unroll
  for (int j = 0; j < 2; ++j)
#pragma unroll
    for (int reg = 0; reg < 4; ++reg)
      Vs[(size_t)(t0 + wm + q * 4 + reg) * 64 + wn + j * 16 + r] = acc[j][reg];
}

// ---------------------------------------------------------------------------
// LDS-resident matvec: h'[lane] = u + M[lane][:] . hb[:]
// M stored with stride 68 -> bank (4*row+col)%32: the wave's 64 row reads
// spread across all 8 four-bank groups (structural floor); hb reads are
// same-address broadcasts (free).  Allocator-proof: rounds 1-3 proved the
// compiler refuses to keep a 64-float per-lane matrix row in VGPRs.
// ---------------------------------------------------------------------------
__device__ __forceinline__ float matvec_lds(const float* __restrict__ Mrow,
                                            const float* __restrict__ hb, float u) {
  float a0 = u, a1 = 0.f, a2 = 0.f, a3 = 0.f;
#pragma unroll
  for (int jj = 0; jj < 64; jj += 4) {
    float4 m = *(const float4*)&Mrow[jj];
    float4 hv = *(const float4*)&hb[jj];
    a0 += m.x * hv.x;
    a1 += m.y * hv.y;
    a2 += m.z * hv.z;
    a3 += m.w * hv.w;
  }
  return (a0 + a1) + (a2 + a3);
}

// stage a 64x64 fp32 matrix into [64][68]-padded LDS, 64-thread block.
__device__ __forceinline__ void stage_mat64(float* Mlds, const float* __restrict__ Mg,
                                            int lane) {
#pragma unroll
  for (int i = 0; i < 16; ++i) {
    int row = i * 4 + (lane >> 4);
    int col = (lane & 15) * 4;
    *(float4*)&Mlds[row * 68 + col] = *(const float4*)&Mg[row * 64 + col];
  }
  __syncthreads();
}

// ---------------------------------------------------------------------------
// scan1 (r12): blocks 0..NC1-1 — U-chunk = invd applied to sum of V slabs,
// then wave 0 does the serial 32-step chunk summary (dA in padded LDS).
// block NC1: dA512 = (dA32)^16 via 4 fp32 squarings (~15 us, pins the
// dispatch at ~ its body duration; the 5-squaring head lives in main blk 1).
// ---------------------------------------------------------------------------
__global__ __launch_bounds__(256) void scan1_kernel(const float* __restrict__ V,
                                                    const float* __restrict__ invdT,
                                                    const float* __restrict__ dA,
                                                    const float* __restrict__ dA32,
                                                    float* __restrict__ U,
                                                    float* __restrict__ S,
                                                    float* __restrict__ dA512g,
                                                    int nslab) {
  __shared__ float smem[13056];
  const int tid = threadIdx.x;
  const int c = blockIdx.x;

  if (c == NC1) {
    // fp32 squaring tail: dA32 -> dA64 -> dA128 -> dA256 -> dA512
    float* b0 = smem;
    float* b1 = smem + 4352;
    const int r0 = (tid >> 4) * 4, c0 = (tid & 15) * 4;
    for (int idx = tid; idx < 4096; idx += 256)
      b0[(idx >> 6) * 68 + (idx & 63)] = dA32[idx];
    __syncthreads();
    float acc[16];
    float* p = b0; float* q = b1;
    for (int s = 1; s <= 4; ++s) {
      mmzero(acc); mac44<68, 68>(acc, p, p, r0, c0);
      if (s == 4) mmst<64>(dA512g, acc, r0, c0);
      mmst<68>(q, acc, r0, c0);
      __syncthreads();
      float* t = p; p = q; q = t;
    }
    return;
  }

  float* invs = smem;            // 4096
  float* Vs   = smem + 4096;     // 2048
  float* Us   = smem + 6144;     // 2048
  float* hs0  = smem + 8192;     // 64
  float* hs1  = smem + 8256;     // 64
  float* Md   = smem + 8320;     // 4352 ([64][68] padded dA)

  for (int idx = tid; idx < 4096; idx += 256) invs[idx] = invdT[idx];
  for (int idx = tid; idx < 4096; idx += 256)
    Md[(idx >> 6) * 68 + (idx & 63)] = dA[idx];
  for (int idx = tid; idx < 2048; idx += 256) {
    float v = 0.f;
    for (int s = 0; s < nslab; ++s) v += V[(size_t)s * VSLAB + (size_t)c * 2048 + idx];
    Vs[idx] = v;
  }
  __syncthreads();

  // transform: 2 rows x 4 cols per thread
  const int r0 = (tid >> 4) * 2, c0 = (tid & 15) * 4;
  float a0[4] = {0.f, 0.f, 0.f, 0.f}, a1[4] = {0.f, 0.f, 0.f, 0.f};
#pragma unroll 4
  for (int k = 0; k < 64; k += 4) {
    float4 v0 = *(const float4*)&Vs[r0 * 64 + k];
    float4 v1 = *(const float4*)&Vs[(r0 + 1) * 64 + k];
    float4 y0 = *(const float4*)&invs[(k + 0) * 64 + c0];
    float4 y1 = *(const float4*)&invs[(k + 1) * 64 + c0];
    float4 y2 = *(const float4*)&invs[(k + 2) * 64 + c0];
    float4 y3 = *(const float4*)&invs[(k + 3) * 64 + c0];
    a0[0] += v0.x * y0.x + v0.y * y1.x + v0.z * y2.x + v0.w * y3.x;
    a0[1] += v0.x * y0.y + v0.y * y1.y + v0.z * y2.y + v0.w * y3.y;
    a0[2] += v0.x * y0.z + v0.y * y1.z + v0.z * y2.z + v0.w * y3.z;
    a0[3] += v0.x * y0.w + v0.y * y1.w + v0.z * y2.w + v0.w * y3.w;
    a1[0] += v1.x * y0.x + v1.y * y1.x + v1.z * y2.x + v1.w * y3.x;
    a1[1] += v1.x * y0.y + v1.y * y1.y + v1.z * y2.y + v1.w * y3.y;
    a1[2] += v1.x * y0.z + v1.y * y1.z + v1.z * y2.z + v1.w * y3.z;
    a1[3] += v1.x * y0.w + v1.y * y1.w + v1.z * y2.w + v1.w * y3.w;
  }
  *(float4*)&Us[r0 * 64 + c0] = make_float4(a0[0], a0[1], a0[2], a0[3]);
  *(float4*)&Us[(r0 + 1) * 64 + c0] = make_float4(a1[0], a1[1], a1[2], a1[3]);
  *(float4*)&U[(size_t)(c * 32 + r0) * 64 + c0] = make_float4(a0[0], a0[1], a0[2], a0[3]);
  *(float4*)&U[(size_t)(c * 32 + r0 + 1) * 64 + c0] = make_float4(a1[0], a1[1], a1[2], a1[3]);
  __syncthreads();

  if (tid < 64) {
    const float* row = Md + tid * 68;
    float h = 0.f;
    hs0[tid] = 0.f;
    for (int t = 0; t < T1; ++t) {
      float u = Us[t * 64 + tid];
      h = matvec_lds(row, (t & 1) ? hs1 : hs0, u);
      ((t & 1) ? hs0 : hs1)[tid] = h;
    }
    S[c * 64 + tid] = h;
  }
}

// ---------------------------------------------------------------------------
// mid stage, split into 3 one-wave-per-block kernels (round-4 verified:
// took mid from 47.6 us to sub-visibility).
// ---------------------------------------------------------------------------
__global__ __launch_bounds__(64) void mid1_kernel(const float* __restrict__ S,
                                                  const float* __restrict__ dA32,
                                                  float* __restrict__ S2g) {
  __shared__ float M[64 * 68];
  __shared__ float hs[2][64];
  const int lane = threadIdx.x;
  const int g = blockIdx.x;
  stage_mat64(M, dA32, lane);
  const float* row = M + lane * 68;
  const float* in = S + g * 16 * 64;
  float h = 0.f;
  hs[0][lane] = 0.f;
  for (int t = 0; t < 16; ++t) {
    h = matvec_lds(row, hs[t & 1], in[t * 64 + lane]);
    hs[(t + 1) & 1][lane] = h;
  }
  S2g[g * 64 + lane] = h;
}

__global__ __launch_bounds__(64) void mid2_kernel(const float* __restrict__ S2g,
                                                  const float* __restrict__ dA512,
                                                  float* __restrict__ H2g) {
  __shared__ float M[64 * 68];
  __shared__ float hs[2][64];
  const int lane = threadIdx.x;
  stage_mat64(M, dA512, lane);
  const float* row = M + lane * 68;
  float h = 0.f;
  hs[0][lane] = 0.f;
  for (int t = 0; t < 16; ++t) {
    H2g[t * 64 + lane] = h;
    h = matvec_lds(row, hs[t & 1], S2g[t * 64 + lane]);
    hs[(t + 1) & 1][lane] = h;
  }
}

__global__ __launch_bounds__(64) void mid3_kernel(const float* __restrict__ S,
                                                  const float* __restrict__ dA32,
                                                  const float* __restrict__ H2g,
                                                  float* __restrict__ Hinit) {
  __shared__ float M[64 * 68];
  __shared__ float hs[2][64];
  const int lane = threadIdx.x;
  const int g = blockIdx.x;
  stage_mat64(M, dA32, lane);
  const float* row = M + lane * 68;
  const float* in = S + g * 16 * 64;
  float h = H2g[g * 64 + lane];
  hs[0][lane] = h;
  for (int t = 0; t < 16; ++t) {
    Hinit[(g * 16 + t) * 64 + lane] = h;
    h = matvec_lds(row, hs[t & 1], in[t * 64 + lane]);
    hs[(t + 1) & 1][lane] = h;
  }
}

// ---------------------------------------------------------------------------
// scan2: one wave/block, full-state expansion, dA staged in padded LDS,
// 4-deep prefetch ring on U.
// ---------------------------------------------------------------------------
__global__ __launch_bounds__(64) void scan2_kernel(const float* __restrict__ U,
                                                   const float* __restrict__ dA,
                                                   const float* __restrict__ Hinit,
                                                   float* __restrict__ Ht) {
  __shared__ float M[64 * 68];
  __shared__ float hs[2][64];
  const int tid = threadIdx.x;
  const int c = blockIdx.x;
  stage_mat64(M, dA, tid);
  const float* row = M + tid * 68;
  float h = Hinit[c * 64 + tid];
  hs[0][tid] = h;
  const float* inc = U + (size_t)c * T1 * 64;
  float* outc = Ht + (size_t)c * T1 * 64;
  float up[4];
#pragma unroll
  for (int i = 0; i < 4; ++i) up[i] = inc[i * 64 + tid];

  for (int t = 0; t < T1; ++t) {
    float u = up[t & 3];
    if (t + 4 < T1) up[t & 3] = inc[(t + 4) * 64 + tid];
    h = matvec_lds(row, hs[t & 1], u);
    hs[(t + 1) & 1][tid] = h;
    outc[t * 64 + tid] = h;
  }
}

// ---------------------------------------------------------------------------
// out: Y[d][t] = (C @ Ht^T)[d][t] + Dp[d]*X[d][t]  via bf16 MFMA (K = 64).
// r4 epilogue (measured-best total); stride 76 for conflict-free MFMA reads.
// ---------------------------------------------------------------------------
__global__ __launch_bounds__(256) void out_kernel(const float* __restrict__ X,
                                                  const float* __restrict__ C,
                                                  const float* __restrict__ Dp,
                                                  const float* __restrict__ Ht,
                                                  float* __restrict__ Y) {
  __shared__ short Cs[64 * 76];      // [d][n] bf16
  __shared__ short Hs[64 * 76];      // [t][n] bf16
  const int tid = threadIdx.x;
  const int lane = tid & 63, w = tid >> 6;
  const int t0 = blockIdx.x * 64;
  const int d0 = blockIdx.y * 64;
  const int q = lane >> 4, r = lane & 15;
  const int brow = lane >> 3, bkc = (lane & 7) * 8;

#pragma unroll
  for (int p = 0; p < 2; ++p) {
    int row = p * 32 + w * 8 + brow;
    float4 c0 = *(const float4*)&C[(size_t)(d0 + row) * 64 + bkc];
    float4 c1 = *(const float4*)&C[(size_t)(d0 + row) * 64 + bkc + 4];
    float4 h0 = *(const float4*)&Ht[(size_t)(t0 + row) * 64 + bkc];
    float4 h1 = *(const float4*)&Ht[(size_t)(t0 + row) * 64 + bkc + 4];
    bf16x8 cv, hv;
    cv[0] = f2bf(c0.x); cv[1] = f2bf(c0.y); cv[2] = f2bf(c0.z); cv[3] = f2bf(c0.w);
    cv[4] = f2bf(c1.x); cv[5] = f2bf(c1.y); cv[6] = f2bf(c1.z); cv[7] = f2bf(c1.w);
    hv[0] = f2bf(h0.x); hv[1] = f2bf(h0.y); hv[2] = f2bf(h0.z); hv[3] = f2bf(h0.w);
    hv[4] = f2bf(h1.x); hv[5] = f2bf(h1.y); hv[6] = f2bf(h1.z); hv[7] = f2bf(h1.w);
    *(bf16x8*)&Cs[row * 76 + bkc] = cv;
    *(bf16x8*)&Hs[row * 76 + bkc] = hv;
  }
  __syncthreads();

  f32x4 acc[4];
#pragma unroll
  for (int j = 0; j < 4; ++j) acc[j] = (f32x4){0.f, 0.f, 0.f, 0.f};
#pragma unroll
  for (int ks = 0; ks < 64; ks += 32) {
    bf16x8 a = *(const bf16x8*)&Cs[(w * 16 + r) * 76 + ks + q * 8];
#pragma unroll
    for (int j = 0; j < 4; ++j) {
      bf16x8 bb = *(const bf16x8*)&Hs[(j * 16 + r) * 76 + ks + q * 8];
      acc[j] = __builtin_amdgcn_mfma_f32_16x16x32_bf16(a, bb, acc[j], 0, 0, 0);
    }
  }

#pragma unroll
  for (int reg = 0; reg < 4; ++reg) {
    int d = d0 + w * 16 + q * 4 + reg;
    float dp = Dp[d];
#pragma unroll
    for (int j = 0; j < 4; ++j) {
      int t = t0 + j * 16 + r;
      size_t off = (size_t)d * LSEQ + t;
      Y[off] = acc[j][reg] + dp * X[off];
    }
  }
}

// ---------------------------------------------------------------------------
extern "C" void kernel_launch(void* const* d_in, const int* in_sizes, int n_in,
                              void* d_out, int out_size, void* d_ws, size_t ws_size,
                              hipStream_t stream) {
  const float* X  = (const float*)d_in[0];
  const float* A  = (const float*)d_in[1];
  const float* B  = (const float*)d_in[2];
  const float* Cm = (const float*)d_in[3];
  const float* Dp = (const float*)d_in[4];
  const float* ld = (const float*)d_in[5];
  float* out = (float*)d_out;
  float* ws = (float*)d_ws;

  // 4 K-slabs if workspace allows (10.2 MB), else 2 (6.2 MB)
  const size_t need4 =
      (size_t)(16384 + 4 * VSLAB + VSLAB + 16384 + 16384 + 2048) * 4;
  const int nslab = (ws_size >= need4) ? 4 : 2;

  float* invdT = ws;                       // 4096
  float* dA    = ws + 4096;                // 4096
  float* dA32  = ws + 8192;                // 4096
  float* dA512 = ws + 12288;               // 4096
  float* V     = ws + 16384;               // nslab * 524288
  float* U     = V + (size_t)nslab * VSLAB; // 524288
  float* S     = U + VSLAB;                // 16384
  float* Hinit = S + 16384;                // 16384
  float* S2g   = Hinit + 16384;            // 1024
  float* H2g   = S2g + 1024;               // 1024
  float* Ht    = V;                         // overlay: V dead after scan1

  main_kernel<<<nslab * 256 + 2, 256, 0, stream>>>(X, A, B, ld, invdT, dA,
                                                   dA32, V, 2048 / nslab);
  scan1_kernel<<<NC1 + 1, 256, 0, stream>>>(V, invdT, dA, dA32, U, S, dA512,
                                            nslab);
  mid1_kernel<<<16, 64, 0, stream>>>(S, dA32, S2g);
  mid2_kernel<<<1, 64, 0, stream>>>(S2g, dA512, H2g);
  mid3_kernel<<<16, 64, 0, stream>>>(S, dA32, H2g, Hinit);
  scan2_kernel<<<NC1, 64, 0, stream>>>(U, dA, Hinit, Ht);
  out_kernel<<<dim3(128, 32), 256, 0, stream>>>(X, Cm, Dp, Ht, out);
}

// Round 13
// 226.953 us; speedup vs baseline: 1.0793x; 1.0383x over previous
//
#include <hip/hip_runtime.h>
#include <math.h>

#define D_CH 2048
#define LSEQ 8192
#define T1 32
#define NC1 256          // LSEQ / T1
#define VSLAB 524288     // per-slab V floats (8192*64)

typedef __attribute__((ext_vector_type(8))) short bf16x8;
typedef __attribute__((ext_vector_type(4))) short bf16x4;
typedef __attribute__((ext_vector_type(4))) float f32x4;

__device__ __forceinline__ short f2bf(float x) {
  unsigned u = __float_as_uint(x);
  u += 0x7FFFu + ((u >> 16) & 1);       // round-to-nearest-even
  return (short)(u >> 16);
}

// ---------------------------------------------------------------------------
// fp32 4x4-register-tile 64x64 matmul helpers on LDS (numerically critical
// dA-power chain stays fp32: squaring DOUBLES relative exponent error, so
// bf16 squarings diverge — measured: 65% output error with bf16 chain).
// Single-CU 64^3 matmul cost ~3.8-4.2 us (calibrated r11: 13 matmuls = 55us).
// Stride 68 is REQUIRED: x-reads hit 4 rows 4 apart; 4*68 % 32 = 16 (distinct
// banks) while 4*64 % 32 = 0 (4-way conflict).
// ---------------------------------------------------------------------------
__device__ __forceinline__ void mmzero(float acc[16]) {
#pragma unroll
  for (int t = 0; t < 16; ++t) acc[t] = 0.f;
}

template <int SZ>
__device__ __forceinline__ void mmld(float acc[16], const float* __restrict__ Z,
                                     int r0, int c0) {
#pragma unroll
  for (int i = 0; i < 4; ++i) {
    float4 z = *(const float4*)&Z[(r0 + i) * SZ + c0];
    acc[i * 4 + 0] = z.x; acc[i * 4 + 1] = z.y;
    acc[i * 4 + 2] = z.z; acc[i * 4 + 3] = z.w;
  }
}

template <int SX, int SY>
__device__ __forceinline__ void mac44(float acc[16], const float* __restrict__ Xb,
                                      const float* __restrict__ Yb, int r0, int c0) {
#pragma unroll 4
  for (int k = 0; k < 64; k += 4) {
    float4 x0 = *(const float4*)&Xb[(r0 + 0) * SX + k];
    float4 x1 = *(const float4*)&Xb[(r0 + 1) * SX + k];
    float4 x2 = *(const float4*)&Xb[(r0 + 2) * SX + k];
    float4 x3 = *(const float4*)&Xb[(r0 + 3) * SX + k];
    float4 y0 = *(const float4*)&Yb[(k + 0) * SY + c0];
    float4 y1 = *(const float4*)&Yb[(k + 1) * SY + c0];
    float4 y2 = *(const float4*)&Yb[(k + 2) * SY + c0];
    float4 y3 = *(const float4*)&Yb[(k + 3) * SY + c0];
#define MROW(i, xi) \
    acc[i * 4 + 0] += xi.x * y0.x + xi.y * y1.x + xi.z * y2.x + xi.w * y3.x; \
    acc[i * 4 + 1] += xi.x * y0.y + xi.y * y1.y + xi.z * y2.y + xi.w * y3.y; \
    acc[i * 4 + 2] += xi.x * y0.z + xi.y * y1.z + xi.z * y2.z + xi.w * y3.z; \
    acc[i * 4 + 3] += xi.x * y0.w + xi.y * y1.w + xi.z * y2.w + xi.w * y3.w;
    MROW(0, x0) MROW(1, x1) MROW(2, x2) MROW(3, x3)
#undef MROW
  }
}

template <int SZ>
__device__ __forceinline__ void mmst(float* Dst, const float acc[16], int r0, int c0) {
#pragma unroll
  for (int i = 0; i < 4; ++i)
    *(float4*)&Dst[(r0 + i) * SZ + c0] =
        make_float4(acc[i * 4 + 0], acc[i * 4 + 1], acc[i * 4 + 2], acc[i * 4 + 3]);
}

// ---------------------------------------------------------------------------
// main_kernel (r13 — vectorized X loads):
//   block 0: prep — fp32 Q-chain (S8) -> invdT (delta*Q^T), dA = 2Q-I.
//   block 1: recompute Q-chain (bitwise-identical dA), squarings s=1..5 ->
//     dA32 (9 matmuls ~36 us, hidden under the vgemm shadow — r12 verified).
//   blocks 2..: V[slab] = B @ X (bf16 MFMA, 32t x 64n tiles).
//     r13 change: X loaded VECTORIZED along t (2 x dwordx4 per lane per step,
//     vs 16 scalar dwords in r4..r12 — all five structural variants of the
//     staging order measured 40-45 us with 89% stall; the load SHAPE is the
//     one axis never varied; Guideline-13 measured 2-2.5x for scalar loads).
//     X tile stored TRANSPOSED in LDS [64k][36t-shorts] (8B-aligned short4
//     writes; fragment reads 8 x ds_read_u16, q-rows 8 apart = 16 banks
//     apart -> <=2-way).  B path / prefetch order / V-write unchanged.
// ---------------------------------------------------------------------------
__global__ __launch_bounds__(256) void main_kernel(const float* __restrict__ X,
                                                   const float* __restrict__ A,
                                                   const float* __restrict__ B,
                                                   const float* __restrict__ logd,
                                                   float* __restrict__ invdT,
                                                   float* __restrict__ dAg,
                                                   float* __restrict__ dA32g,
                                                   float* __restrict__ V,
                                                   int KS) {
  __shared__ float smem[8704];           // 34.8 KB union (prep needs it all)
  const int tid = threadIdx.x;
  const int lane = tid & 63;
  const int w = tid >> 6;

  if (blockIdx.x < 2) {
    // ---------------- Q-chain (fp32): Q ~= inv(I - P), ||P|| <= ~0.12 ------
    float* bQ = smem;
    float* bP = smem + 4352;
    const int r0 = (tid >> 4) * 4, c0 = (tid & 15) * 4;
    const float delta = expf(logd[0]);
    const float half = 0.5f * delta;
    float accQ[16], accP[16];

    for (int idx = tid; idx < 4096; idx += 256) {
      int i = idx >> 6, j = idx & 63;
      float p = half * A[idx];
      bP[i * 68 + j] = p;
      bQ[i * 68 + j] = p + (i == j ? 1.f : 0.f);   // S2 = I + P
    }
    __syncthreads();
    // bP = P^2
    mmzero(accP); mac44<68, 68>(accP, bP, bP, r0, c0);
    __syncthreads();
    mmst<68>(bP, accP, r0, c0);
    __syncthreads();
    // 2 doublings: S4 = (I+P^2)S2 (+P^4), S8 = (I+P^4)S4.
#pragma unroll 1
    for (int s = 0; s < 2; ++s) {
      mmld<68>(accQ, bQ, r0, c0);
      mac44<68, 68>(accQ, bP, bQ, r0, c0);        // Q + P^k * Q
      if (s < 1) { mmzero(accP); mac44<68, 68>(accP, bP, bP, r0, c0); }
      __syncthreads();
      mmst<68>(bQ, accQ, r0, c0);
      if (s < 1) mmst<68>(bP, accP, r0, c0);
      __syncthreads();
    }

    if (blockIdx.x == 0) {
      // exports: invdT = delta*Q^T, dA = 2Q - I
      for (int idx = tid; idx < 4096; idx += 256) {
        int n = idx >> 6, m = idx & 63;
        float qv = bQ[n * 68 + m];
        invdT[m * 64 + n] = delta * qv;
        dAg[idx] = 2.f * qv - (n == m ? 1.f : 0.f);
      }
      return;
    }

    // block 1: dA = 2Q - I in place (element-wise), then 5 squarings -> dA32.
    for (int idx = tid; idx < 4096; idx += 256) {
      int i = idx >> 6, j = idx & 63;
      bQ[i * 68 + j] = 2.f * bQ[i * 68 + j] - (i == j ? 1.f : 0.f);
    }
    __syncthreads();
    float acc[16];
    float* p = bQ; float* q = bP;
    for (int s = 1; s <= 5; ++s) {
      mmzero(acc); mac44<68, 68>(acc, p, p, r0, c0);
      if (s == 5) mmst<64>(dA32g, acc, r0, c0);
      mmst<68>(q, acc, r0, c0);
      __syncthreads();
      float* t = p; p = q; q = t;
    }
    return;
  }

  // ------------------------------ vgemm (bf16 MFMA) ------------------------
  const int b = blockIdx.x - 2;
  const int t0 = (b & 255) << 5;         // 256 t-tiles of 32
  const int slab = b >> 8;
  const int k0 = slab * KS;
  short* Xs = (short*)smem;              // [64k][36t] bf16 (transposed tile)
  short* Bs = (short*)smem + 2304;       // [64n][76k] bf16
  const int q = lane >> 4, r = lane & 15;
  const int brow = lane >> 3;            // 0..7
  const int bkc = (lane & 7) * 8;        // 0..56
  const int xrow = tid >> 3;             // 0..31 (k-row within half)
  const int xc4 = (tid & 7) * 4;         // 0..28 (t column, float4)
  const int wm = (w & 1) * 16;           // M-half of this wave
  const int wn = (w >> 1) * 32;          // N-half of this wave

  f32x4 acc[2];
#pragma unroll
  for (int j = 0; j < 2; ++j) acc[j] = (f32x4){0.f, 0.f, 0.f, 0.f};

  float4 xv0, xv1;
  float bv[16];

#define LOADX(KK)                                                              \
  xv0 = *(const float4*)&X[(size_t)(k0 + (KK) + xrow) * LSEQ + t0 + xc4];      \
  xv1 = *(const float4*)&X[(size_t)(k0 + (KK) + 32 + xrow) * LSEQ + t0 + xc4];

#define LOADB(KK)                                                              \
  _Pragma("unroll")                                                            \
  for (int pp = 0; pp < 2; ++pp) {                                             \
    int n = pp * 32 + w * 8 + brow;                                            \
    float4 f0 = *(const float4*)&B[(size_t)n * D_CH + k0 + (KK) + bkc];        \
    float4 f1 = *(const float4*)&B[(size_t)n * D_CH + k0 + (KK) + bkc + 4];    \
    bv[pp * 8 + 0] = f0.x; bv[pp * 8 + 1] = f0.y;                              \
    bv[pp * 8 + 2] = f0.z; bv[pp * 8 + 3] = f0.w;                              \
    bv[pp * 8 + 4] = f1.x; bv[pp * 8 + 5] = f1.y;                              \
    bv[pp * 8 + 6] = f1.z; bv[pp * 8 + 7] = f1.w;                              \
  }

  LOADX(0)
  LOADB(0)

  for (int kk = 0; kk < KS; kk += 64) {
    // cvt + LDS write of the tile staged in registers
    bf16x4 xs0, xs1;
    xs0[0] = f2bf(xv0.x); xs0[1] = f2bf(xv0.y);
    xs0[2] = f2bf(xv0.z); xs0[3] = f2bf(xv0.w);
    xs1[0] = f2bf(xv1.x); xs1[1] = f2bf(xv1.y);
    xs1[2] = f2bf(xv1.z); xs1[3] = f2bf(xv1.w);
    *(bf16x4*)&Xs[xrow * 36 + xc4] = xs0;
    *(bf16x4*)&Xs[(32 + xrow) * 36 + xc4] = xs1;
#pragma unroll
    for (int pp = 0; pp < 2; ++pp) {
      bf16x8 bp8;
#pragma unroll
      for (int j = 0; j < 8; ++j) bp8[j] = f2bf(bv[pp * 8 + j]);
      *(bf16x8*)&Bs[(pp * 32 + w * 8 + brow) * 76 + bkc] = bp8;
    }
    __syncthreads();

    // prefetch next K-step into registers (overlaps MFMA + barrier)
    if (kk + 64 < KS) {
      LOADX(kk + 64)
      LOADB(kk + 64)
    }

#pragma unroll
    for (int ks = 0; ks < 64; ks += 32) {
      bf16x8 a;
#pragma unroll
      for (int j = 0; j < 8; ++j)
        a[j] = Xs[(ks + q * 8 + j) * 36 + wm + r];
#pragma unroll
      for (int j = 0; j < 2; ++j) {
        bf16x8 bb = *(const bf16x8*)&Bs[(wn + j * 16 + r) * 76 + ks + q * 8];
        acc[j] = __builtin_amdgcn_mfma_f32_16x16x32_bf16(a, bb, acc[j], 0, 0, 0);
      }
    }
    __syncthreads();
  }
#undef LOADX
#undef LOADB

  float* Vs = V + (size_t)slab * VSLAB;
#pragma unroll
  for (int j = 0; j < 2; ++j)
#pragma unroll
    for (int reg = 0; reg < 4; ++reg)
      Vs[(size_t)(t0 + wm + q * 4 + reg) * 64 + wn + j * 16 + r] = acc[j][reg];
}

// ---------------------------------------------------------------------------
// LDS-resident matvec: h'[lane] = u + M[lane][:] . hb[:]
// M stored with stride 68 -> bank (4*row+col)%32: the wave's 64 row reads
// spread across all 8 four-bank groups (structural floor); hb reads are
// same-address broadcasts (free).  Allocator-proof: rounds 1-3 proved the
// compiler refuses to keep a 64-float per-lane matrix row in VGPRs.
// ---------------------------------------------------------------------------
__device__ __forceinline__ float matvec_lds(const float* __restrict__ Mrow,
                                            const float* __restrict__ hb, float u) {
  float a0 = u, a1 = 0.f, a2 = 0.f, a3 = 0.f;
#pragma unroll
  for (int jj = 0; jj < 64; jj += 4) {
    float4 m = *(const float4*)&Mrow[jj];
    float4 hv = *(const float4*)&hb[jj];
    a0 += m.x * hv.x;
    a1 += m.y * hv.y;
    a2 += m.z * hv.z;
    a3 += m.w * hv.w;
  }
  return (a0 + a1) + (a2 + a3);
}

// stage a 64x64 fp32 matrix into [64][68]-padded LDS, 64-thread block.
__device__ __forceinline__ void stage_mat64(float* Mlds, const float* __restrict__ Mg,
                                            int lane) {
#pragma unroll
  for (int i = 0; i < 16; ++i) {
    int row = i * 4 + (lane >> 4);
    int col = (lane & 15) * 4;
    *(float4*)&Mlds[row * 68 + col] = *(const float4*)&Mg[row * 64 + col];
  }
  __syncthreads();
}

// ---------------------------------------------------------------------------
// scan1 (r12 structure): blocks 0..NC1-1 — U-chunk = invd applied to sum of V
// slabs, then wave 0 does the serial 32-step chunk summary (dA in padded
// LDS).  block NC1: dA512 = (dA32)^16 via 4 fp32 squarings.
// ---------------------------------------------------------------------------
__global__ __launch_bounds__(256) void scan1_kernel(const float* __restrict__ V,
                                                    const float* __restrict__ invdT,
                                                    const float* __restrict__ dA,
                                                    const float* __restrict__ dA32,
                                                    float* __restrict__ U,
                                                    float* __restrict__ S,
                                                    float* __restrict__ dA512g,
                                                    int nslab) {
  __shared__ float smem[13056];
  const int tid = threadIdx.x;
  const int c = blockIdx.x;

  if (c == NC1) {
    // fp32 squaring tail: dA32 -> dA64 -> dA128 -> dA256 -> dA512
    float* b0 = smem;
    float* b1 = smem + 4352;
    const int r0 = (tid >> 4) * 4, c0 = (tid & 15) * 4;
    for (int idx = tid; idx < 4096; idx += 256)
      b0[(idx >> 6) * 68 + (idx & 63)] = dA32[idx];
    __syncthreads();
    float acc[16];
    float* p = b0; float* q = b1;
    for (int s = 1; s <= 4; ++s) {
      mmzero(acc); mac44<68, 68>(acc, p, p, r0, c0);
      if (s == 4) mmst<64>(dA512g, acc, r0, c0);
      mmst<68>(q, acc, r0, c0);
      __syncthreads();
      float* t = p; p = q; q = t;
    }
    return;
  }

  float* invs = smem;            // 4096
  float* Vs   = smem + 4096;     // 2048
  float* Us   = smem + 6144;     // 2048
  float* hs0  = smem + 8192;     // 64
  float* hs1  = smem + 8256;     // 64
  float* Md   = smem + 8320;     // 4352 ([64][68] padded dA)

  for (int idx = tid; idx < 4096; idx += 256) invs[idx] = invdT[idx];
  for (int idx = tid; idx < 4096; idx += 256)
    Md[(idx >> 6) * 68 + (idx & 63)] = dA[idx];
  for (int idx = tid; idx < 2048; idx += 256) {
    float v = 0.f;
    for (int s = 0; s < nslab; ++s) v += V[(size_t)s * VSLAB + (size_t)c * 2048 + idx];
    Vs[idx] = v;
  }
  __syncthreads();

  // transform: 2 rows x 4 cols per thread
  const int r0 = (tid >> 4) * 2, c0 = (tid & 15) * 4;
  float a0[4] = {0.f, 0.f, 0.f, 0.f}, a1[4] = {0.f, 0.f, 0.f, 0.f};
#pragma unroll 4
  for (int k = 0; k < 64; k += 4) {
    float4 v0 = *(const float4*)&Vs[r0 * 64 + k];
    float4 v1 = *(const float4*)&Vs[(r0 + 1) * 64 + k];
    float4 y0 = *(const float4*)&invs[(k + 0) * 64 + c0];
    float4 y1 = *(const float4*)&invs[(k + 1) * 64 + c0];
    float4 y2 = *(const float4*)&invs[(k + 2) * 64 + c0];
    float4 y3 = *(const float4*)&invs[(k + 3) * 64 + c0];
    a0[0] += v0.x * y0.x + v0.y * y1.x + v0.z * y2.x + v0.w * y3.x;
    a0[1] += v0.x * y0.y + v0.y * y1.y + v0.z * y2.y + v0.w * y3.y;
    a0[2] += v0.x * y0.z + v0.y * y1.z + v0.z * y2.z + v0.w * y3.z;
    a0[3] += v0.x * y0.w + v0.y * y1.w + v0.z * y2.w + v0.w * y3.w;
    a1[0] += v1.x * y0.x + v1.y * y1.x + v1.z * y2.x + v1.w * y3.x;
    a1[1] += v1.x * y0.y + v1.y * y1.y + v1.z * y2.y + v1.w * y3.y;
    a1[2] += v1.x * y0.z + v1.y * y1.z + v1.z * y2.z + v1.w * y3.z;
    a1[3] += v1.x * y0.w + v1.y * y1.w + v1.z * y2.w + v1.w * y3.w;
  }
  *(float4*)&Us[r0 * 64 + c0] = make_float4(a0[0], a0[1], a0[2], a0[3]);
  *(float4*)&Us[(r0 + 1) * 64 + c0] = make_float4(a1[0], a1[1], a1[2], a1[3]);
  *(float4*)&U[(size_t)(c * 32 + r0) * 64 + c0] = make_float4(a0[0], a0[1], a0[2], a0[3]);
  *(float4*)&U[(size_t)(c * 32 + r0 + 1) * 64 + c0] = make_float4(a1[0], a1[1], a1[2], a1[3]);
  __syncthreads();

  if (tid < 64) {
    const float* row = Md + tid * 68;
    float h = 0.f;
    hs0[tid] = 0.f;
    for (int t = 0; t < T1; ++t) {
      float u = Us[t * 64 + tid];
      h = matvec_lds(row, (t & 1) ? hs1 : hs0, u);
      ((t & 1) ? hs0 : hs1)[tid] = h;
    }
    S[c * 64 + tid] = h;
  }
}

// ---------------------------------------------------------------------------
// mid stage, split into 3 one-wave-per-block kernels (round-4 verified:
// took mid from 47.6 us to sub-visibility).
// ---------------------------------------------------------------------------
__global__ __launch_bounds__(64) void mid1_kernel(const float* __restrict__ S,
                                                  const float* __restrict__ dA32,
                                                  float* __restrict__ S2g) {
  __shared__ float M[64 * 68];
  __shared__ float hs[2][64];
  const int lane = threadIdx.x;
  const int g = blockIdx.x;
  stage_mat64(M, dA32, lane);
  const float* row = M + lane * 68;
  const float* in = S + g * 16 * 64;
  float h = 0.f;
  hs[0][lane] = 0.f;
  for (int t = 0; t < 16; ++t) {
    h = matvec_lds(row, hs[t & 1], in[t * 64 + lane]);
    hs[(t + 1) & 1][lane] = h;
  }
  S2g[g * 64 + lane] = h;
}

__global__ __launch_bounds__(64) void mid2_kernel(const float* __restrict__ S2g,
                                                  const float* __restrict__ dA512,
                                                  float* __restrict__ H2g) {
  __shared__ float M[64 * 68];
  __shared__ float hs[2][64];
  const int lane = threadIdx.x;
  stage_mat64(M, dA512, lane);
  const float* row = M + lane * 68;
  float h = 0.f;
  hs[0][lane] = 0.f;
  for (int t = 0; t < 16; ++t) {
    H2g[t * 64 + lane] = h;
    h = matvec_lds(row, hs[t & 1], S2g[t * 64 + lane]);
    hs[(t + 1) & 1][lane] = h;
  }
}

__global__ __launch_bounds__(64) void mid3_kernel(const float* __restrict__ S,
                                                  const float* __restrict__ dA32,
                                                  const float* __restrict__ H2g,
                                                  float* __restrict__ Hinit) {
  __shared__ float M[64 * 68];
  __shared__ float hs[2][64];
  const int lane = threadIdx.x;
  const int g = blockIdx.x;
  stage_mat64(M, dA32, lane);
  const float* row = M + lane * 68;
  const float* in = S + g * 16 * 64;
  float h = H2g[g * 64 + lane];
  hs[0][lane] = h;
  for (int t = 0; t < 16; ++t) {
    Hinit[(g * 16 + t) * 64 + lane] = h;
    h = matvec_lds(row, hs[t & 1], in[t * 64 + lane]);
    hs[(t + 1) & 1][lane] = h;
  }
}

// ---------------------------------------------------------------------------
// scan2: one wave/block, full-state expansion, dA staged in padded LDS,
// 4-deep prefetch ring on U.
// ---------------------------------------------------------------------------
__global__ __launch_bounds__(64) void scan2_kernel(const float* __restrict__ U,
                                                   const float* __restrict__ dA,
                                                   const float* __restrict__ Hinit,
                                                   float* __restrict__ Ht) {
  __shared__ float M[64 * 68];
  __shared__ float hs[2][64];
  const int tid = threadIdx.x;
  const int c = blockIdx.x;
  stage_mat64(M, dA, tid);
  const float* row = M + tid * 68;
  float h = Hinit[c * 64 + tid];
  hs[0][tid] = h;
  const float* inc = U + (size_t)c * T1 * 64;
  float* outc = Ht + (size_t)c * T1 * 64;
  float up[4];
#pragma unroll
  for (int i = 0; i < 4; ++i) up[i] = inc[i * 64 + tid];

  for (int t = 0; t < T1; ++t) {
    float u = up[t & 3];
    if (t + 4 < T1) up[t & 3] = inc[(t + 4) * 64 + tid];
    h = matvec_lds(row, hs[t & 1], u);
    hs[(t + 1) & 1][tid] = h;
    outc[t * 64 + tid] = h;
  }
}

// ---------------------------------------------------------------------------
// out: Y[d][t] = (C @ Ht^T)[d][t] + Dp[d]*X[d][t]  via bf16 MFMA (K = 64).
// r4 epilogue (measured-best total); stride 76 for conflict-free MFMA reads.
// ---------------------------------------------------------------------------
__global__ __launch_bounds__(256) void out_kernel(const float* __restrict__ X,
                                                  const float* __restrict__ C,
                                                  const float* __restrict__ Dp,
                                                  const float* __restrict__ Ht,
                                                  float* __restrict__ Y) {
  __shared__ short Cs[64 * 76];      // [d][n] bf16
  __shared__ short Hs[64 * 76];      // [t][n] bf16
  const int tid = threadIdx.x;
  const int lane = tid & 63, w = tid >> 6;
  const int t0 = blockIdx.x * 64;
  const int d0 = blockIdx.y * 64;
  const int q = lane >> 4, r = lane & 15;
  const int brow = lane >> 3, bkc = (lane & 7) * 8;

#pragma unroll
  for (int p = 0; p < 2; ++p) {
    int row = p * 32 + w * 8 + brow;
    float4 c0 = *(const float4*)&C[(size_t)(d0 + row) * 64 + bkc];
    float4 c1 = *(const float4*)&C[(size_t)(d0 + row) * 64 + bkc + 4];
    float4 h0 = *(const float4*)&Ht[(size_t)(t0 + row) * 64 + bkc];
    float4 h1 = *(const float4*)&Ht[(size_t)(t0 + row) * 64 + bkc + 4];
    bf16x8 cv, hv;
    cv[0] = f2bf(c0.x); cv[1] = f2bf(c0.y); cv[2] = f2bf(c0.z); cv[3] = f2bf(c0.w);
    cv[4] = f2bf(c1.x); cv[5] = f2bf(c1.y); cv[6] = f2bf(c1.z); cv[7] = f2bf(c1.w);
    hv[0] = f2bf(h0.x); hv[1] = f2bf(h0.y); hv[2] = f2bf(h0.z); hv[3] = f2bf(h0.w);
    hv[4] = f2bf(h1.x); hv[5] = f2bf(h1.y); hv[6] = f2bf(h1.z); hv[7] = f2bf(h1.w);
    *(bf16x8*)&Cs[row * 76 + bkc] = cv;
    *(bf16x8*)&Hs[row * 76 + bkc] = hv;
  }
  __syncthreads();

  f32x4 acc[4];
#pragma unroll
  for (int j = 0; j < 4; ++j) acc[j] = (f32x4){0.f, 0.f, 0.f, 0.f};
#pragma unroll
  for (int ks = 0; ks < 64; ks += 32) {
    bf16x8 a = *(const bf16x8*)&Cs[(w * 16 + r) * 76 + ks + q * 8];
#pragma unroll
    for (int j = 0; j < 4; ++j) {
      bf16x8 bb = *(const bf16x8*)&Hs[(j * 16 + r) * 76 + ks + q * 8];
      acc[j] = __builtin_amdgcn_mfma_f32_16x16x32_bf16(a, bb, acc[j], 0, 0, 0);
    }
  }

#pragma unroll
  for (int reg = 0; reg < 4; ++reg) {
    int d = d0 + w * 16 + q * 4 + reg;
    float dp = Dp[d];
#pragma unroll
    for (int j = 0; j < 4; ++j) {
      int t = t0 + j * 16 + r;
      size_t off = (size_t)d * LSEQ + t;
      Y[off] = acc[j][reg] + dp * X[off];
    }
  }
}

// ---------------------------------------------------------------------------
extern "C" void kernel_launch(void* const* d_in, const int* in_sizes, int n_in,
                              void* d_out, int out_size, void* d_ws, size_t ws_size,
                              hipStream_t stream) {
  const float* X  = (const float*)d_in[0];
  const float* A  = (const float*)d_in[1];
  const float* B  = (const float*)d_in[2];
  const float* Cm = (const float*)d_in[3];
  const float* Dp = (const float*)d_in[4];
  const float* ld = (const float*)d_in[5];
  float* out = (float*)d_out;
  float* ws = (float*)d_ws;

  // 4 K-slabs if workspace allows (10.2 MB), else 2 (6.2 MB)
  const size_t need4 =
      (size_t)(16384 + 4 * VSLAB + VSLAB + 16384 + 16384 + 2048) * 4;
  const int nslab = (ws_size >= need4) ? 4 : 2;

  float* invdT = ws;                       // 4096
  float* dA    = ws + 4096;                // 4096
  float* dA32  = ws + 8192;                // 4096
  float* dA512 = ws + 12288;               // 4096
  float* V     = ws + 16384;               // nslab * 524288
  float* U     = V + (size_t)nslab * VSLAB; // 524288
  float* S     = U + VSLAB;                // 16384
  float* Hinit = S + 16384;                // 16384
  float* S2g   = Hinit + 16384;            // 1024
  float* H2g   = S2g + 1024;               // 1024
  float* Ht    = V;                         // overlay: V dead after scan1

  main_kernel<<<nslab * 256 + 2, 256, 0, stream>>>(X, A, B, ld, invdT, dA,
                                                   dA32, V, 2048 / nslab);
  scan1_kernel<<<NC1 + 1, 256, 0, stream>>>(V, invdT, dA, dA32, U, S, dA512,
                                            nslab);
  mid1_kernel<<<16, 64, 0, stream>>>(S, dA32, S2g);
  mid2_kernel<<<1, 64, 0, stream>>>(S2g, dA512, H2g);
  mid3_kernel<<<16, 64, 0, stream>>>(S, dA32, H2g, Hinit);
  scan2_kernel<<<NC1, 64, 0, stream>>>(U, dA, Hinit, Ht);
  out_kernel<<<dim3(128, 32), 256, 0, stream>>>(X, Cm, Dp, Ht, out);
}